// Round 1
// baseline (419.257 us; speedup 1.0000x reference)
//
#include <hip/hip_runtime.h>
#include <hip/hip_cooperative_groups.h>
#include <math.h>

namespace cg = cooperative_groups;

#define EPS      0.1f
#define INV_EPS  10.0f
#define THRESH   0.1f
#define MAX_IT   20

// Problem sizes (fixed by reference setup_inputs)
#define BB 4
#define NN 1024
#define MM 1024
#define DD 512

// workspace layout (float offsets). Total ~33.7 MB.
#define OFF_C    ((size_t)0)                   // C  [B,N,M]
#define OFF_CT   ((size_t)4194304)             // CT [B,M,N]
#define OFF_NX   ((size_t)8388608)             // |x_i| [B*N]
#define OFF_NY   (OFF_NX + 4096)               // |y_j| [B*M]
#define OFF_U    (OFF_NY + 4096)               // u     [B*N]
#define OFF_UN   (OFF_U  + 4096)               // u_new [B*N]
#define OFF_V    (OFF_UN + 4096)               // v     [B*M]
#define OFF_LNU  (OFF_V  + 4096)               // log(nu+1e-8) [B*M]
#define OFF_ERR  (OFF_LNU + 4096)              // err accum per iteration [32]
#define OFF_DONE (OFF_ERR + 32)                // done flag (int)

__device__ __forceinline__ float wave_reduce_sum(float x) {
#pragma unroll
  for (int off = 32; off > 0; off >>= 1) x += __shfl_xor(x, off, 64);
  return x;
}
__device__ __forceinline__ float wave_reduce_max(float x) {
#pragma unroll
  for (int off = 32; off > 0; off >>= 1) x = fmaxf(x, __shfl_xor(x, off, 64));
  return x;
}

// -------- init: zero state, precompute log(nu + 1e-8), zero d_out --------
__global__ void __launch_bounds__(256) init_kernel(const float* __restrict__ nu,
                                                   float* u, float* un, float* v,
                                                   float* log_nu, float* err_acc,
                                                   int* done, float* out) {
  int t = blockIdx.x * 256 + threadIdx.x;
  if (t < BB * NN) {
    u[t] = 0.f;
    un[t] = 0.f;
    v[t] = 0.f;
    log_nu[t] = logf(nu[t] + 1e-8f);
  }
  if (t < 32) err_acc[t] = 0.f;
  if (t == 0) *done = 0;
  if (t < BB) out[t] = 0.f;
}

// -------- row norms of x (-> nx) and y (-> ny); one wave per 512-float row --------
__global__ void __launch_bounds__(256) norms_kernel(const float* __restrict__ x,
                                                    const float* __restrict__ y,
                                                    float* __restrict__ nx,
                                                    float* __restrict__ ny) {
  const int tid = threadIdx.x;
  const int w = tid >> 6, lane = tid & 63;
  const int r = blockIdx.x * 4 + w;                 // 0..8191
  const float* src = (r < BB * NN) ? (x + (size_t)r * DD)
                                   : (y + (size_t)(r - BB * NN) * DD);
  const float4* s4 = (const float4*)src;
  float4 a = s4[lane];
  float4 b = s4[lane + 64];
  float ss = a.x * a.x + a.y * a.y + a.z * a.z + a.w * a.w +
             b.x * b.x + b.y * b.y + b.z * b.z + b.w * b.w;
  ss = wave_reduce_sum(ss);
  if (lane == 0) {
    float n = sqrtf(ss);
    if (r < BB * NN) nx[r] = n; else ny[r - BB * NN] = n;
  }
}

// -------- fp32 tiled GEMM: dot = X Y^T, epilogue C = 1 - dot/denom, writes C and CT --------
__global__ void __launch_bounds__(256) gemm_kernel(const float* __restrict__ x,
                                                   const float* __restrict__ y,
                                                   const float* __restrict__ nxg,
                                                   const float* __restrict__ nyg,
                                                   float* __restrict__ C,
                                                   float* __restrict__ CT) {
  __shared__ float As[16][68];   // k-major, padded: 2-way max bank alias
  __shared__ float Bs[16][68];
  __shared__ float Ct[64][65];   // transpose staging
  const int b = blockIdx.z;
  const int i0 = blockIdx.y * 64;
  const int j0 = blockIdx.x * 64;
  const int tid = threadIdx.x;
  const int tx = tid & 15, ty = tid >> 4;
  const int il = tid >> 2;              // 0..63 (tile row)
  const int kq = (tid & 3) << 2;        // 0,4,8,12 (k sub-chunk)

  const float* xb = x + ((size_t)b * NN + i0 + il) * DD + kq;
  const float* yb = y + ((size_t)b * MM + j0 + il) * DD + kq;

  float acc[4][4] = {{0.f, 0.f, 0.f, 0.f}, {0.f, 0.f, 0.f, 0.f},
                     {0.f, 0.f, 0.f, 0.f}, {0.f, 0.f, 0.f, 0.f}};

  for (int k0 = 0; k0 < DD; k0 += 16) {
    float4 av = *(const float4*)(xb + k0);
    float4 bv = *(const float4*)(yb + k0);
    __syncthreads();
    As[kq + 0][il] = av.x; As[kq + 1][il] = av.y; As[kq + 2][il] = av.z; As[kq + 3][il] = av.w;
    Bs[kq + 0][il] = bv.x; Bs[kq + 1][il] = bv.y; Bs[kq + 2][il] = bv.z; Bs[kq + 3][il] = bv.w;
    __syncthreads();
#pragma unroll
    for (int kk = 0; kk < 16; ++kk) {
      float4 a = *(const float4*)&As[kk][ty * 4];
      float4 bq = *(const float4*)&Bs[kk][tx * 4];
      float ar[4] = {a.x, a.y, a.z, a.w};
      float br[4] = {bq.x, bq.y, bq.z, bq.w};
#pragma unroll
      for (int ii = 0; ii < 4; ++ii)
#pragma unroll
        for (int jj = 0; jj < 4; ++jj)
          acc[ii][jj] = fmaf(ar[ii], br[jj], acc[ii][jj]);
    }
  }

  float nxv[4], nyv[4];
#pragma unroll
  for (int ii = 0; ii < 4; ++ii) nxv[ii] = nxg[b * NN + i0 + ty * 4 + ii];
#pragma unroll
  for (int jj = 0; jj < 4; ++jj) nyv[jj] = nyg[b * MM + j0 + tx * 4 + jj];

#pragma unroll
  for (int ii = 0; ii < 4; ++ii)
#pragma unroll
    for (int jj = 0; jj < 4; ++jj) {
      float den = fmaxf(nxv[ii] * nyv[jj], 1e-8f);
      acc[ii][jj] = 1.0f - acc[ii][jj] / den;
    }

  // C: coalesced float4 stores
#pragma unroll
  for (int ii = 0; ii < 4; ++ii) {
    float4 cv = make_float4(acc[ii][0], acc[ii][1], acc[ii][2], acc[ii][3]);
    *(float4*)(C + ((size_t)b * NN + i0 + ty * 4 + ii) * MM + j0 + tx * 4) = cv;
  }
  // CT via LDS transpose
  __syncthreads();
#pragma unroll
  for (int ii = 0; ii < 4; ++ii)
#pragma unroll
    for (int jj = 0; jj < 4; ++jj)
      Ct[ty * 4 + ii][tx * 4 + jj] = acc[ii][jj];
  __syncthreads();
#pragma unroll
  for (int jj = 0; jj < 4; ++jj) {
    int jl = ty * 4 + jj;
    float4 tv = make_float4(Ct[tx * 4 + 0][jl], Ct[tx * 4 + 1][jl],
                            Ct[tx * 4 + 2][jl], Ct[tx * 4 + 3][jl]);
    *(float4*)(CT + ((size_t)b * MM + j0 + jl) * NN + i0 + tx * 4) = tv;
  }
}

// row LSE of (pot[j] - row[j]) * INV_EPS over 1024 elements, one wave per row.
// Butterfly reduce -> all lanes hold the result.
__device__ __forceinline__ float lse_row(const float4* __restrict__ row,
                                         const float4* __restrict__ pot, int lane) {
  float t[16];
  float mx = -1e30f;
#pragma unroll
  for (int q = 0; q < 4; ++q) {
    int f = lane + q * 64;
    float4 c = row[f];
    float4 p = pot[f];
    t[q * 4 + 0] = (p.x - c.x) * INV_EPS;
    t[q * 4 + 1] = (p.y - c.y) * INV_EPS;
    t[q * 4 + 2] = (p.z - c.z) * INV_EPS;
    t[q * 4 + 3] = (p.w - c.w) * INV_EPS;
    mx = fmaxf(mx, fmaxf(fmaxf(t[q * 4 + 0], t[q * 4 + 1]),
                         fmaxf(t[q * 4 + 2], t[q * 4 + 3])));
  }
  mx = wave_reduce_max(mx);
  float s = 0.f;
#pragma unroll
  for (int k = 0; k < 16; ++k) s += __expf(t[k] - mx);
  s = wave_reduce_sum(s);
  return mx + __logf(s);
}

// -------- cooperative Sinkhorn loop + final transport cost --------
// 512 blocks x 256 threads (2 blocks/CU guaranteed co-resident).
// Each block owns 8 contiguous rows (same batch), 2 rows per wave.
// u_new[i] = eps*log_mu - eps*LSE_j((v_j - C_ij)/eps)   (u cancels exactly)
// v_new[j] = eps*log_nu - eps*LSE_i((u_new_i - C_ij)/eps) (v cancels exactly)
__global__ void __launch_bounds__(256) sinkhorn_kernel(
    const float* __restrict__ C, const float* __restrict__ CT,
    float* u, float* u_new, float* v,
    const float* __restrict__ log_nu,
    float* err_acc, int* done, float* out) {
  cg::grid_group grid = cg::this_grid();
  const int tid = threadIdx.x;
  const int bid = blockIdx.x;
  const int lane = tid & 63;
  const int w = tid >> 6;
  const int gt = bid * 256 + tid;
  __shared__ float s_red;
  const float eps_log_mu = EPS * __logf(1.0f / (float)NN + 1e-8f);

  for (int it = 0; it < MAX_IT; ++it) {
    if (it) grid.sync();
    if (__hip_atomic_load(done, __ATOMIC_RELAXED, __HIP_MEMORY_SCOPE_AGENT)) break;

    // ---- row pass: update u_new, accumulate err = sum_i |u_new - u| ----
    if (tid == 0) s_red = 0.f;
    __syncthreads();
    float werr = 0.f;
#pragma unroll
    for (int rr = 0; rr < 2; ++rr) {
      const int r = bid * 8 + w * 2 + rr;   // (b,i) row id
      const int b = r >> 10;
      float lse = lse_row((const float4*)(C + (size_t)r * MM),
                          (const float4*)(v + b * MM), lane);
      float un = eps_log_mu - EPS * lse;
      if (lane == 0) {
        u_new[r] = un;
        werr += fabsf(un - u[r]);
      }
    }
    if (lane == 0) atomicAdd(&s_red, werr);
    __syncthreads();
    if (tid == 0) atomicAdd(err_acc + it, s_red);

    grid.sync();

    // ---- col pass: update v from u_new; commit u; update done ----
#pragma unroll
    for (int rr = 0; rr < 2; ++rr) {
      const int r = bid * 8 + w * 2 + rr;   // (b,j) row id
      const int b = r >> 10;
      float lse = lse_row((const float4*)(CT + (size_t)r * NN),
                          (const float4*)(u_new + b * NN), lane);
      if (lane == 0) v[r] = EPS * log_nu[r] - EPS * lse;
    }
    if (gt < BB * NN) u[gt] = u_new[gt];
    if (gt == 0) {
      float err = err_acc[it] * (1.0f / (float)BB);
      if (err < THRESH)
        __hip_atomic_store(done, 1, __ATOMIC_RELAXED, __HIP_MEMORY_SCOPE_AGENT);
    }
  }

  grid.sync();

  // ---- final cost: out[b] = sum_ij exp((u_i + v_j - C_ij)/eps) * C_ij ----
  if (tid == 0) s_red = 0.f;
  __syncthreads();
  float wcost = 0.f;
#pragma unroll
  for (int rr = 0; rr < 2; ++rr) {
    const int r = bid * 8 + w * 2 + rr;
    const int b = r >> 10;
    const float ui = u[r];
    const float4* crow = (const float4*)(C + (size_t)r * MM);
    const float4* vb = (const float4*)(v + b * MM);
    float s = 0.f;
#pragma unroll
    for (int q = 0; q < 4; ++q) {
      int f = lane + q * 64;
      float4 c = crow[f];
      float4 p = vb[f];
      s += __expf((ui + p.x - c.x) * INV_EPS) * c.x;
      s += __expf((ui + p.y - c.y) * INV_EPS) * c.y;
      s += __expf((ui + p.z - c.z) * INV_EPS) * c.z;
      s += __expf((ui + p.w - c.w) * INV_EPS) * c.w;
    }
    s = wave_reduce_sum(s);
    if (lane == 0) wcost += s;
  }
  if (lane == 0) atomicAdd(&s_red, wcost);
  __syncthreads();
  if (tid == 0) atomicAdd(out + (bid >> 7), s_red);  // 8 rows/block -> same b
}

extern "C" void kernel_launch(void* const* d_in, const int* in_sizes, int n_in,
                              void* d_out, int out_size, void* d_ws, size_t ws_size,
                              hipStream_t stream) {
  const float* x = (const float*)d_in[0];
  const float* y = (const float*)d_in[1];
  const float* nu = (const float*)d_in[2];
  float* out = (float*)d_out;
  float* ws = (float*)d_ws;

  float* C = ws + OFF_C;
  float* CT = ws + OFF_CT;
  float* nx = ws + OFF_NX;
  float* ny = ws + OFF_NY;
  float* u = ws + OFF_U;
  float* un = ws + OFF_UN;
  float* v = ws + OFF_V;
  float* lnu = ws + OFF_LNU;
  float* err = ws + OFF_ERR;
  int* done = (int*)(ws + OFF_DONE);

  init_kernel<<<16, 256, 0, stream>>>(nu, u, un, v, lnu, err, done, out);
  norms_kernel<<<2048, 256, 0, stream>>>(x, y, nx, ny);
  gemm_kernel<<<dim3(16, 16, 4), 256, 0, stream>>>(x, y, nx, ny, C, CT);

  void* args[] = {(void*)&C, (void*)&CT, (void*)&u, (void*)&un, (void*)&v,
                  (void*)&lnu, (void*)&err, (void*)&done, (void*)&out};
  hipLaunchCooperativeKernel(reinterpret_cast<void*>(&sinkhorn_kernel),
                             dim3(512), dim3(256), args, 0, stream);
}

// Round 2
// 197.415 us; speedup vs baseline: 2.1237x; 2.1237x over previous
//
#include <hip/hip_runtime.h>
#include <math.h>

#define EPS      0.1f
#define INV_EPS  10.0f
#define THRESH   0.1f
#define MAX_IT   20

// Problem sizes (fixed by reference setup_inputs)
#define BB 4
#define NN 1024
#define MM 1024
#define DD 512

// Sinkhorn loop config: 128 blocks x 512 threads, 32 rows/block, 4 rows/wave
#define GBLK 128
#define TBLK 512

// workspace layout (float offsets)
#define OFF_C    ((size_t)0)                   // C  [B,N,M]
#define OFF_CT   ((size_t)4194304)             // CT [B,M,N]
#define OFF_NX   ((size_t)8388608)             // |x_i| [B*N]
#define OFF_NY   (OFF_NX + 4096)               // |y_j| [B*M]
#define OFF_UN   (OFF_NY + 4096)               // u_new [B*N]
#define OFF_V    (OFF_UN + 4096)               // v     [B*M]
#define OFF_LNU  (OFF_V  + 4096)               // log(nu+1e-8) [B*M]
#define OFF_ERR  (OFF_LNU + 4096)              // err accum per iteration [32]
#define OFF_BAR  (OFF_ERR + 32)                // barrier state [64 ints]

__device__ __forceinline__ float wave_reduce_sum(float x) {
#pragma unroll
  for (int off = 32; off > 0; off >>= 1) x += __shfl_xor(x, off, 64);
  return x;
}
__device__ __forceinline__ float wave_reduce_max(float x) {
#pragma unroll
  for (int off = 32; off > 0; off >>= 1) x = fmaxf(x, __shfl_xor(x, off, 64));
  return x;
}

// -------- init: zero state, precompute log(nu + 1e-8), zero d_out --------
__global__ void __launch_bounds__(256) init_kernel(const float* __restrict__ nu,
                                                   float* v, float* log_nu,
                                                   float* err_acc, int* bar,
                                                   float* out) {
  int t = blockIdx.x * 256 + threadIdx.x;
  if (t < BB * MM) {
    v[t] = 0.f;
    log_nu[t] = logf(nu[t] + 1e-8f);
  }
  if (t < 32) err_acc[t] = 0.f;
  if (t < 64) bar[t] = 0;
  if (t < BB) out[t] = 0.f;
}

// -------- row norms of x (-> nx) and y (-> ny); one wave per 512-float row --------
__global__ void __launch_bounds__(256) norms_kernel(const float* __restrict__ x,
                                                    const float* __restrict__ y,
                                                    float* __restrict__ nx,
                                                    float* __restrict__ ny) {
  const int tid = threadIdx.x;
  const int w = tid >> 6, lane = tid & 63;
  const int r = blockIdx.x * 4 + w;                 // 0..8191
  const float* src = (r < BB * NN) ? (x + (size_t)r * DD)
                                   : (y + (size_t)(r - BB * NN) * DD);
  const float4* s4 = (const float4*)src;
  float4 a = s4[lane];
  float4 b = s4[lane + 64];
  float ss = a.x * a.x + a.y * a.y + a.z * a.z + a.w * a.w +
             b.x * b.x + b.y * b.y + b.z * b.z + b.w * b.w;
  ss = wave_reduce_sum(ss);
  if (lane == 0) {
    float n = sqrtf(ss);
    if (r < BB * NN) nx[r] = n; else ny[r - BB * NN] = n;
  }
}

// -------- fp32 tiled GEMM: dot = X Y^T, epilogue C = 1 - dot/denom, writes C and CT --------
__global__ void __launch_bounds__(256) gemm_kernel(const float* __restrict__ x,
                                                   const float* __restrict__ y,
                                                   const float* __restrict__ nxg,
                                                   const float* __restrict__ nyg,
                                                   float* __restrict__ C,
                                                   float* __restrict__ CT) {
  __shared__ float As[16][68];
  __shared__ float Bs[16][68];
  __shared__ float Ct[64][65];
  const int b = blockIdx.z;
  const int i0 = blockIdx.y * 64;
  const int j0 = blockIdx.x * 64;
  const int tid = threadIdx.x;
  const int tx = tid & 15, ty = tid >> 4;
  const int il = tid >> 2;
  const int kq = (tid & 3) << 2;

  const float* xb = x + ((size_t)b * NN + i0 + il) * DD + kq;
  const float* yb = y + ((size_t)b * MM + j0 + il) * DD + kq;

  float acc[4][4] = {{0.f, 0.f, 0.f, 0.f}, {0.f, 0.f, 0.f, 0.f},
                     {0.f, 0.f, 0.f, 0.f}, {0.f, 0.f, 0.f, 0.f}};

  for (int k0 = 0; k0 < DD; k0 += 16) {
    float4 av = *(const float4*)(xb + k0);
    float4 bv = *(const float4*)(yb + k0);
    __syncthreads();
    As[kq + 0][il] = av.x; As[kq + 1][il] = av.y; As[kq + 2][il] = av.z; As[kq + 3][il] = av.w;
    Bs[kq + 0][il] = bv.x; Bs[kq + 1][il] = bv.y; Bs[kq + 2][il] = bv.z; Bs[kq + 3][il] = bv.w;
    __syncthreads();
#pragma unroll
    for (int kk = 0; kk < 16; ++kk) {
      float4 a = *(const float4*)&As[kk][ty * 4];
      float4 bq = *(const float4*)&Bs[kk][tx * 4];
      float ar[4] = {a.x, a.y, a.z, a.w};
      float br[4] = {bq.x, bq.y, bq.z, bq.w};
#pragma unroll
      for (int ii = 0; ii < 4; ++ii)
#pragma unroll
        for (int jj = 0; jj < 4; ++jj)
          acc[ii][jj] = fmaf(ar[ii], br[jj], acc[ii][jj]);
    }
  }

  float nxv[4], nyv[4];
#pragma unroll
  for (int ii = 0; ii < 4; ++ii) nxv[ii] = nxg[b * NN + i0 + ty * 4 + ii];
#pragma unroll
  for (int jj = 0; jj < 4; ++jj) nyv[jj] = nyg[b * MM + j0 + tx * 4 + jj];

#pragma unroll
  for (int ii = 0; ii < 4; ++ii)
#pragma unroll
    for (int jj = 0; jj < 4; ++jj) {
      float den = fmaxf(nxv[ii] * nyv[jj], 1e-8f);
      acc[ii][jj] = 1.0f - acc[ii][jj] / den;
    }

#pragma unroll
  for (int ii = 0; ii < 4; ++ii) {
    float4 cv = make_float4(acc[ii][0], acc[ii][1], acc[ii][2], acc[ii][3]);
    *(float4*)(C + ((size_t)b * NN + i0 + ty * 4 + ii) * MM + j0 + tx * 4) = cv;
  }
  __syncthreads();
#pragma unroll
  for (int ii = 0; ii < 4; ++ii)
#pragma unroll
    for (int jj = 0; jj < 4; ++jj)
      Ct[ty * 4 + ii][tx * 4 + jj] = acc[ii][jj];
  __syncthreads();
#pragma unroll
  for (int jj = 0; jj < 4; ++jj) {
    int jl = ty * 4 + jj;
    float4 tv = make_float4(Ct[tx * 4 + 0][jl], Ct[tx * 4 + 1][jl],
                            Ct[tx * 4 + 2][jl], Ct[tx * 4 + 3][jl]);
    *(float4*)(CT + ((size_t)b * MM + j0 + jl) * NN + i0 + tx * 4) = tv;
  }
}

// row LSE of (pot[j] - row[j]) * INV_EPS over 1024 elems; pot staged in LDS.
// Butterfly reduce -> all lanes hold the result.
__device__ __forceinline__ float lse_row(const float4* __restrict__ row,
                                         const float4* __restrict__ pot, int lane) {
  float t[16];
  float mx = -1e30f;
#pragma unroll
  for (int q = 0; q < 4; ++q) {
    int f = lane + q * 64;
    float4 c = row[f];
    float4 p = pot[f];
    t[q * 4 + 0] = (p.x - c.x) * INV_EPS;
    t[q * 4 + 1] = (p.y - c.y) * INV_EPS;
    t[q * 4 + 2] = (p.z - c.z) * INV_EPS;
    t[q * 4 + 3] = (p.w - c.w) * INV_EPS;
    mx = fmaxf(mx, fmaxf(fmaxf(t[q * 4 + 0], t[q * 4 + 1]),
                         fmaxf(t[q * 4 + 2], t[q * 4 + 3])));
  }
  mx = wave_reduce_max(mx);
  float s = 0.f;
#pragma unroll
  for (int k = 0; k < 16; ++k) s += __expf(t[k] - mx);
  s = wave_reduce_sum(s);
  return mx + __logf(s);
}

// Fence-free grid barrier: all cross-block data travels via agent-scope
// relaxed atomics (bypassing non-coherent per-XCD L2); each wave drains its
// outstanding stores (s_waitcnt vmcnt(0)) before block arrival. No buffer_inv
// is ever emitted, so C/CT stay L2-resident across the whole loop.
__device__ __forceinline__ void grid_barrier(int* arrive, int* genp, int& gen, int tid) {
  asm volatile("s_waitcnt vmcnt(0)" ::: "memory");
  __syncthreads();
  ++gen;
  if (tid == 0) {
    int total = __hip_atomic_fetch_add(arrive, 1, __ATOMIC_RELAXED,
                                       __HIP_MEMORY_SCOPE_AGENT) + 1;
    if (total == gen * GBLK) {
      __hip_atomic_store(genp, gen, __ATOMIC_RELAXED, __HIP_MEMORY_SCOPE_AGENT);
    } else {
      while (__hip_atomic_load(genp, __ATOMIC_RELAXED, __HIP_MEMORY_SCOPE_AGENT) < gen)
        __builtin_amdgcn_s_sleep(2);
    }
  }
  __syncthreads();
}

// -------- persistent Sinkhorn loop + final transport cost --------
// u_new[i] = eps*log_mu - eps*LSE_j((v_j - C_ij)/eps)     (u cancels exactly)
// v_new[j] = eps*log_nu - eps*LSE_i((u_new_i - C_ij)/eps) (v cancels exactly)
// u_prev lives in registers of the owning wave (same rows every iteration).
__global__ void __launch_bounds__(TBLK) sinkhorn_kernel(
    const float* __restrict__ C, const float* __restrict__ CT,
    float* __restrict__ un, float* __restrict__ v,
    const float* __restrict__ log_nu,
    float* __restrict__ err_acc, int* __restrict__ bar, float* __restrict__ out) {
  const int tid = threadIdx.x;
  const int bid = blockIdx.x;
  const int lane = tid & 63;
  const int w = tid >> 6;                 // 0..7
  const int b = bid >> 5;                 // batch (32 blocks per batch)
  const int rbase = (bid & 31) * 32;      // first owned row within batch
  int* arrive = bar;
  int* genp = bar + 32;
  int gen = 0;

  __shared__ float sv[1024];
  __shared__ float s_red;
  __shared__ float s_err;

  const float eps_log_mu = EPS * __logf(1.0f / (float)NN + 1e-8f);
  float u_prev[4] = {0.f, 0.f, 0.f, 0.f};

  for (int it = 0; it < MAX_IT; ++it) {
    // ---- row pass: u_new from v ----
    if (tid == 0) s_red = 0.f;
    for (int q = tid; q < MM; q += TBLK)
      sv[q] = __hip_atomic_load(v + b * MM + q, __ATOMIC_RELAXED, __HIP_MEMORY_SCOPE_AGENT);
    __syncthreads();

    float werr = 0.f;
#pragma unroll
    for (int rr = 0; rr < 4; ++rr) {
      const int r = rbase + w * 4 + rr;
      float lse = lse_row((const float4*)(C + ((size_t)b * NN + r) * MM),
                          (const float4*)sv, lane);
      float unv = eps_log_mu - EPS * lse;
      werr += fabsf(unv - u_prev[rr]);
      u_prev[rr] = unv;
      if (lane == 0)
        __hip_atomic_store(un + b * NN + r, unv, __ATOMIC_RELAXED, __HIP_MEMORY_SCOPE_AGENT);
    }
    if (lane == 0) atomicAdd(&s_red, werr);
    __syncthreads();
    if (tid == 0)
      __hip_atomic_fetch_add(err_acc + it, s_red, __ATOMIC_RELAXED, __HIP_MEMORY_SCOPE_AGENT);

    grid_barrier(arrive, genp, gen, tid);   // publish un + err

    if (tid == 0)
      s_err = __hip_atomic_load(err_acc + it, __ATOMIC_RELAXED, __HIP_MEMORY_SCOPE_AGENT);
    __syncthreads();
    const bool conv = (s_err * (1.0f / (float)BB) < THRESH);

    // ---- col pass: v from u_new ----
    for (int q = tid; q < NN; q += TBLK)
      sv[q] = __hip_atomic_load(un + b * NN + q, __ATOMIC_RELAXED, __HIP_MEMORY_SCOPE_AGENT);
    __syncthreads();

#pragma unroll
    for (int rr = 0; rr < 4; ++rr) {
      const int c = rbase + w * 4 + rr;
      float lse = lse_row((const float4*)(CT + ((size_t)b * MM + c) * NN),
                          (const float4*)sv, lane);
      float vv = EPS * log_nu[b * MM + c] - EPS * lse;
      if (lane == 0)
        __hip_atomic_store(v + b * MM + c, vv, __ATOMIC_RELAXED, __HIP_MEMORY_SCOPE_AGENT);
    }

    grid_barrier(arrive, genp, gen, tid);   // publish v

    if (conv) break;   // uniform across all blocks (s_err is a global sum)
  }

  // ---- final cost: out[b] = sum_ij exp((u_i + v_j - C_ij)/eps) * C_ij ----
  if (tid == 0) s_red = 0.f;
  for (int q = tid; q < MM; q += TBLK)
    sv[q] = __hip_atomic_load(v + b * MM + q, __ATOMIC_RELAXED, __HIP_MEMORY_SCOPE_AGENT);
  __syncthreads();

  float wcost = 0.f;
#pragma unroll
  for (int rr = 0; rr < 4; ++rr) {
    const int r = rbase + w * 4 + rr;
    const float ui = u_prev[rr];
    const float4* crow = (const float4*)(C + ((size_t)b * NN + r) * MM);
    const float4* vb = (const float4*)sv;
    float s = 0.f;
#pragma unroll
    for (int q = 0; q < 4; ++q) {
      int f = lane + q * 64;
      float4 c = crow[f];
      float4 p = vb[f];
      s += __expf((ui + p.x - c.x) * INV_EPS) * c.x;
      s += __expf((ui + p.y - c.y) * INV_EPS) * c.y;
      s += __expf((ui + p.z - c.z) * INV_EPS) * c.z;
      s += __expf((ui + p.w - c.w) * INV_EPS) * c.w;
    }
    s = wave_reduce_sum(s);
    if (lane == 0) wcost += s;
  }
  if (lane == 0) atomicAdd(&s_red, wcost);
  __syncthreads();
  if (tid == 0) atomicAdd(out + b, s_red);
}

extern "C" void kernel_launch(void* const* d_in, const int* in_sizes, int n_in,
                              void* d_out, int out_size, void* d_ws, size_t ws_size,
                              hipStream_t stream) {
  const float* x = (const float*)d_in[0];
  const float* y = (const float*)d_in[1];
  const float* nu = (const float*)d_in[2];
  float* out = (float*)d_out;
  float* ws = (float*)d_ws;

  float* C = ws + OFF_C;
  float* CT = ws + OFF_CT;
  float* nx = ws + OFF_NX;
  float* ny = ws + OFF_NY;
  float* un = ws + OFF_UN;
  float* v = ws + OFF_V;
  float* lnu = ws + OFF_LNU;
  float* err = ws + OFF_ERR;
  int* bar = (int*)(ws + OFF_BAR);

  init_kernel<<<16, 256, 0, stream>>>(nu, v, lnu, err, bar, out);
  norms_kernel<<<2048, 256, 0, stream>>>(x, y, nx, ny);
  gemm_kernel<<<dim3(16, 16, 4), 256, 0, stream>>>(x, y, nx, ny, C, CT);

  void* args[] = {(void*)&C, (void*)&CT, (void*)&un, (void*)&v,
                  (void*)&lnu, (void*)&err, (void*)&bar, (void*)&out};
  hipLaunchCooperativeKernel(reinterpret_cast<void*>(&sinkhorn_kernel),
                             dim3(GBLK), dim3(TBLK), args, 0, stream);
}

// Round 3
// 155.281 us; speedup vs baseline: 2.7000x; 1.2713x over previous
//
#include <hip/hip_runtime.h>
#include <math.h>

#define EPS      0.1f
#define INV_EPS  10.0f
#define THRESH   0.1f
#define MAX_IT   20

// Problem sizes (fixed by reference setup_inputs)
#define BB 4
#define NN 1024
#define MM 1024
#define DD 512

// Sinkhorn loop config: 128 blocks x 512 threads, 32 rows/block, 4 rows/wave
#define GBLK 128
#define TBLK 512

// workspace layout (float offsets)
#define OFF_C    ((size_t)0)                   // C  [B,N,M]
#define OFF_CT   ((size_t)4194304)             // CT [B,M,N]
#define OFF_NX   ((size_t)8388608)             // |x_i| [B*N]
#define OFF_NY   (OFF_NX + 4096)               // |y_j| [B*M]
#define OFF_UN   (OFF_NY + 4096)               // u_new [B*N]
#define OFF_V    (OFF_UN + 4096)               // v     [B*M]
#define OFF_LNU  (OFF_V  + 4096)               // log(nu+1e-8) [B*M]
#define OFF_ERR  (OFF_LNU + 4096)              // err accum per iteration [32]
#define OFF_BAR  (OFF_ERR + 32)                // barrier state [64 ints]

typedef __bf16 bf16x8 __attribute__((ext_vector_type(8)));
typedef float f32x4 __attribute__((ext_vector_type(4)));

__device__ __forceinline__ float wave_reduce_sum(float x) {
#pragma unroll
  for (int off = 32; off > 0; off >>= 1) x += __shfl_xor(x, off, 64);
  return x;
}
__device__ __forceinline__ float wave_reduce_max(float x) {
#pragma unroll
  for (int off = 32; off > 0; off >>= 1) x = fmaxf(x, __shfl_xor(x, off, 64));
  return x;
}

// -------- norms of x/y rows + init of sinkhorn state (merged) --------
__global__ void __launch_bounds__(256) norms_kernel(const float* __restrict__ x,
                                                    const float* __restrict__ y,
                                                    float* __restrict__ nx,
                                                    float* __restrict__ ny,
                                                    const float* __restrict__ nu,
                                                    float* v, float* log_nu,
                                                    float* err_acc, int* bar,
                                                    float* out) {
  const int tid = threadIdx.x;
  // init portion (blocks 0..15 cover 4096 threads)
  int gt = blockIdx.x * 256 + tid;
  if (gt < BB * MM) {
    v[gt] = 0.f;
    log_nu[gt] = logf(nu[gt] + 1e-8f);
  }
  if (gt < 32) err_acc[gt] = 0.f;
  if (gt < 64) bar[gt] = 0;
  if (gt < BB) out[gt] = 0.f;

  const int w = tid >> 6, lane = tid & 63;
  const int r = blockIdx.x * 4 + w;                 // 0..8191
  const float* src = (r < BB * NN) ? (x + (size_t)r * DD)
                                   : (y + (size_t)(r - BB * NN) * DD);
  const float4* s4 = (const float4*)src;
  float4 a = s4[lane];
  float4 b = s4[lane + 64];
  float ss = a.x * a.x + a.y * a.y + a.z * a.z + a.w * a.w +
             b.x * b.x + b.y * b.y + b.z * b.z + b.w * b.w;
  ss = wave_reduce_sum(ss);
  if (lane == 0) {
    float n = sqrtf(ss);
    if (r < BB * NN) nx[r] = n; else ny[r - BB * NN] = n;
  }
}

// split fp32 -> (hi, lo) bf16 pair by truncation; hi+lo captures ~16 mantissa bits
__device__ __forceinline__ void cvt4(float4 f, uint2& ph, uint2& pl) {
  uint b0 = __float_as_uint(f.x), b1 = __float_as_uint(f.y);
  uint b2 = __float_as_uint(f.z), b3 = __float_as_uint(f.w);
  ph.x = (b0 >> 16) | (b1 & 0xffff0000u);
  ph.y = (b2 >> 16) | (b3 & 0xffff0000u);
  float r0 = f.x - __uint_as_float(b0 & 0xffff0000u);
  float r1 = f.y - __uint_as_float(b1 & 0xffff0000u);
  float r2 = f.z - __uint_as_float(b2 & 0xffff0000u);
  float r3 = f.w - __uint_as_float(b3 & 0xffff0000u);
  pl.x = (__float_as_uint(r0) >> 16) | (__float_as_uint(r1) & 0xffff0000u);
  pl.y = (__float_as_uint(r2) >> 16) | (__float_as_uint(r3) & 0xffff0000u);
}

// -------- MFMA split-bf16 GEMM: dot = X Y^T (3 passes: hh + hl + lh),
// epilogue C = 1 - dot/denom, writes C and CT. 64x128 tile, 256 thr. --------
__global__ void __launch_bounds__(256) gemm_kernel(const float* __restrict__ x,
                                                   const float* __restrict__ y,
                                                   const float* __restrict__ nxg,
                                                   const float* __restrict__ nyg,
                                                   float* __restrict__ C,
                                                   float* __restrict__ CT) {
  __shared__ ushort Ah[64 * 32], Al[64 * 32];     // 4 KB each
  __shared__ ushort Bh[128 * 32], Bl[128 * 32];   // 8 KB each
  __shared__ float Tt[32 * 68];                   // transpose staging, 8.5 KB
  __shared__ float s_nx[64], s_ny[128];

  const int b = blockIdx.z;
  const int i0 = blockIdx.y * 64;    // m-tile
  const int j0 = blockIdx.x * 128;   // n-tile
  const int t = threadIdx.x;
  const int w = t >> 6, lane = t & 63;
  const int m16 = lane & 15, q = lane >> 4;
  const int wm = (w & 1) * 32, wn = (w >> 1) * 64;

  const int srow = t >> 3;            // 0..31 staging row within pass
  const int skq = (t & 7) * 4;        // staging k-offset (floats)

  const float* xb = x + ((size_t)b * NN + i0 + srow) * DD + skq;
  const float* yb = y + ((size_t)b * MM + j0 + srow) * DD + skq;

  f32x4 acc[2][4];
#pragma unroll
  for (int mi = 0; mi < 2; ++mi)
#pragma unroll
    for (int ni = 0; ni < 4; ++ni) acc[mi][ni] = (f32x4)0.f;

  for (int k0 = 0; k0 < DD; k0 += 32) {
    float4 ax[2], by[4];
#pragma unroll
    for (int p = 0; p < 2; ++p) ax[p] = *(const float4*)(xb + (size_t)p * 32 * DD + k0);
#pragma unroll
    for (int p = 0; p < 4; ++p) by[p] = *(const float4*)(yb + (size_t)p * 32 * DD + k0);
    __syncthreads();
#pragma unroll
    for (int p = 0; p < 2; ++p) {
      uint2 ph, pl;
      cvt4(ax[p], ph, pl);
      *(uint2*)&Ah[(srow + p * 32) * 32 + skq] = ph;
      *(uint2*)&Al[(srow + p * 32) * 32 + skq] = pl;
    }
#pragma unroll
    for (int p = 0; p < 4; ++p) {
      uint2 ph, pl;
      cvt4(by[p], ph, pl);
      *(uint2*)&Bh[(srow + p * 32) * 32 + skq] = ph;
      *(uint2*)&Bl[(srow + p * 32) * 32 + skq] = pl;
    }
    __syncthreads();

    bf16x8 ahf[2], alf[2], bhf[4], blf[4];
#pragma unroll
    for (int mi = 0; mi < 2; ++mi) {
      const int ai = (wm + mi * 16 + m16) * 32 + q * 8;
      ahf[mi] = *(const bf16x8*)&Ah[ai];
      alf[mi] = *(const bf16x8*)&Al[ai];
    }
#pragma unroll
    for (int ni = 0; ni < 4; ++ni) {
      const int bi = (wn + ni * 16 + m16) * 32 + q * 8;
      bhf[ni] = *(const bf16x8*)&Bh[bi];
      blf[ni] = *(const bf16x8*)&Bl[bi];
    }
#pragma unroll
    for (int mi = 0; mi < 2; ++mi)
#pragma unroll
      for (int ni = 0; ni < 4; ++ni) {
        acc[mi][ni] = __builtin_amdgcn_mfma_f32_16x16x32_bf16(ahf[mi], bhf[ni], acc[mi][ni], 0, 0, 0);
        acc[mi][ni] = __builtin_amdgcn_mfma_f32_16x16x32_bf16(ahf[mi], blf[ni], acc[mi][ni], 0, 0, 0);
        acc[mi][ni] = __builtin_amdgcn_mfma_f32_16x16x32_bf16(alf[mi], bhf[ni], acc[mi][ni], 0, 0, 0);
      }
  }

  // epilogue: C = 1 - dot/denom
  if (t < 64) s_nx[t] = nxg[b * NN + i0 + t];
  else if (t < 192) s_ny[t - 64] = nyg[b * MM + j0 + t - 64];
  __syncthreads();

#pragma unroll
  for (int mi = 0; mi < 2; ++mi)
#pragma unroll
    for (int ni = 0; ni < 4; ++ni)
#pragma unroll
      for (int r = 0; r < 4; ++r) {
        const int m = wm + mi * 16 + q * 4 + r;
        const int n = wn + ni * 16 + m16;
        float den = fmaxf(s_nx[m] * s_ny[n], 1e-8f);
        float cv = 1.0f - acc[mi][ni][r] / den;
        acc[mi][ni][r] = cv;
        C[((size_t)b * NN + i0 + m) * MM + j0 + n] = cv;
      }

  // CT via 4-pass LDS transpose (32 n-rows per pass)
#pragma unroll
  for (int p = 0; p < 4; ++p) {
    __syncthreads();
    if ((wn >> 5) == (p & 2)) {          // wn=0 -> p 0,1 ; wn=64 -> p 2,3
      const int ni0 = ((p * 32 - wn) >> 4);
#pragma unroll
      for (int nn2 = 0; nn2 < 2; ++nn2) {
        const int ni = ni0 + nn2;
        const int nl = ni * 16 + m16 - p * 32 + wn;   // 0..31
#pragma unroll
        for (int mi = 0; mi < 2; ++mi)
#pragma unroll
          for (int r = 0; r < 4; ++r)
            Tt[nl * 68 + wm + mi * 16 + q * 4 + r] = acc[mi][ni][r];
      }
    }
    __syncthreads();
    const int row = t >> 3;
    const int off = (t & 7) * 8;
    float4 v0 = *(float4*)&Tt[row * 68 + off];
    float4 v1 = *(float4*)&Tt[row * 68 + off + 4];
    float* dst = CT + ((size_t)b * MM + j0 + p * 32 + row) * NN + i0 + off;
    *(float4*)dst = v0;
    *(float4*)(dst + 4) = v1;
  }
}

// row LSE of (pot[j] - row[j]) * INV_EPS over 1024 elems; pot staged in LDS.
__device__ __forceinline__ float lse_row(const float4* __restrict__ row,
                                         const float4* __restrict__ pot, int lane) {
  float t[16];
  float mx = -1e30f;
#pragma unroll
  for (int q = 0; q < 4; ++q) {
    int f = lane + q * 64;
    float4 c = row[f];
    float4 p = pot[f];
    t[q * 4 + 0] = (p.x - c.x) * INV_EPS;
    t[q * 4 + 1] = (p.y - c.y) * INV_EPS;
    t[q * 4 + 2] = (p.z - c.z) * INV_EPS;
    t[q * 4 + 3] = (p.w - c.w) * INV_EPS;
    mx = fmaxf(mx, fmaxf(fmaxf(t[q * 4 + 0], t[q * 4 + 1]),
                         fmaxf(t[q * 4 + 2], t[q * 4 + 3])));
  }
  mx = wave_reduce_max(mx);
  float s = 0.f;
#pragma unroll
  for (int k = 0; k < 16; ++k) s += __expf(t[k] - mx);
  s = wave_reduce_sum(s);
  return mx + __logf(s);
}

// Fence-free grid barrier (see round-1 notes): cross-block data via agent-scope
// relaxed atomics; per-wave vmcnt(0) drain before arrival; no L2 invalidates.
__device__ __forceinline__ void grid_barrier(int* arrive, int* genp, int& gen, int tid) {
  asm volatile("s_waitcnt vmcnt(0)" ::: "memory");
  __syncthreads();
  ++gen;
  if (tid == 0) {
    int total = __hip_atomic_fetch_add(arrive, 1, __ATOMIC_RELAXED,
                                       __HIP_MEMORY_SCOPE_AGENT) + 1;
    if (total == gen * GBLK) {
      __hip_atomic_store(genp, gen, __ATOMIC_RELAXED, __HIP_MEMORY_SCOPE_AGENT);
    } else {
      while (__hip_atomic_load(genp, __ATOMIC_RELAXED, __HIP_MEMORY_SCOPE_AGENT) < gen)
        __builtin_amdgcn_s_sleep(2);
    }
  }
  __syncthreads();
}

// -------- persistent Sinkhorn loop + final transport cost --------
__global__ void __launch_bounds__(TBLK) sinkhorn_kernel(
    const float* __restrict__ C, const float* __restrict__ CT,
    float* __restrict__ un, float* __restrict__ v,
    const float* __restrict__ log_nu,
    float* __restrict__ err_acc, int* __restrict__ bar, float* __restrict__ out) {
  const int tid = threadIdx.x;
  const int bid = blockIdx.x;
  const int lane = tid & 63;
  const int w = tid >> 6;                 // 0..7
  const int b = bid >> 5;                 // batch (32 blocks per batch)
  const int rbase = (bid & 31) * 32;      // first owned row within batch
  int* arrive = bar;
  int* genp = bar + 32;
  int gen = 0;

  __shared__ float sv[1024];
  __shared__ float s_red;
  __shared__ float s_err;

  const float eps_log_mu = EPS * __logf(1.0f / (float)NN + 1e-8f);
  float u_prev[4] = {0.f, 0.f, 0.f, 0.f};

  for (int it = 0; it < MAX_IT; ++it) {
    // ---- row pass: u_new from v ----
    if (tid == 0) s_red = 0.f;
    for (int q = tid; q < MM; q += TBLK)
      sv[q] = __hip_atomic_load(v + b * MM + q, __ATOMIC_RELAXED, __HIP_MEMORY_SCOPE_AGENT);
    __syncthreads();

    float werr = 0.f;
#pragma unroll
    for (int rr = 0; rr < 4; ++rr) {
      const int r = rbase + w * 4 + rr;
      float lse = lse_row((const float4*)(C + ((size_t)b * NN + r) * MM),
                          (const float4*)sv, lane);
      float unv = eps_log_mu - EPS * lse;
      werr += fabsf(unv - u_prev[rr]);
      u_prev[rr] = unv;
      if (lane == 0)
        __hip_atomic_store(un + b * NN + r, unv, __ATOMIC_RELAXED, __HIP_MEMORY_SCOPE_AGENT);
    }
    if (lane == 0) atomicAdd(&s_red, werr);
    __syncthreads();
    if (tid == 0)
      __hip_atomic_fetch_add(err_acc + it, s_red, __ATOMIC_RELAXED, __HIP_MEMORY_SCOPE_AGENT);

    grid_barrier(arrive, genp, gen, tid);   // publish un + err

    if (tid == 0)
      s_err = __hip_atomic_load(err_acc + it, __ATOMIC_RELAXED, __HIP_MEMORY_SCOPE_AGENT);
    __syncthreads();
    const bool conv = (s_err * (1.0f / (float)BB) < THRESH);

    // ---- col pass: v from u_new ----
    for (int q = tid; q < NN; q += TBLK)
      sv[q] = __hip_atomic_load(un + b * NN + q, __ATOMIC_RELAXED, __HIP_MEMORY_SCOPE_AGENT);
    __syncthreads();

#pragma unroll
    for (int rr = 0; rr < 4; ++rr) {
      const int c = rbase + w * 4 + rr;
      float lse = lse_row((const float4*)(CT + ((size_t)b * MM + c) * NN),
                          (const float4*)sv, lane);
      float vv = EPS * log_nu[b * MM + c] - EPS * lse;
      if (lane == 0)
        __hip_atomic_store(v + b * MM + c, vv, __ATOMIC_RELAXED, __HIP_MEMORY_SCOPE_AGENT);
    }

    grid_barrier(arrive, genp, gen, tid);   // publish v

    if (conv) break;   // uniform across all blocks (s_err is a global sum)
  }

  // ---- final cost: out[b] = sum_ij exp((u_i + v_j - C_ij)/eps) * C_ij ----
  if (tid == 0) s_red = 0.f;
  for (int q = tid; q < MM; q += TBLK)
    sv[q] = __hip_atomic_load(v + b * MM + q, __ATOMIC_RELAXED, __HIP_MEMORY_SCOPE_AGENT);
  __syncthreads();

  float wcost = 0.f;
#pragma unroll
  for (int rr = 0; rr < 4; ++rr) {
    const int r = rbase + w * 4 + rr;
    const float ui = u_prev[rr];
    const float4* crow = (const float4*)(C + ((size_t)b * NN + r) * MM);
    const float4* vb = (const float4*)sv;
    float s = 0.f;
#pragma unroll
    for (int q = 0; q < 4; ++q) {
      int f = lane + q * 64;
      float4 c = crow[f];
      float4 p = vb[f];
      s += __expf((ui + p.x - c.x) * INV_EPS) * c.x;
      s += __expf((ui + p.y - c.y) * INV_EPS) * c.y;
      s += __expf((ui + p.z - c.z) * INV_EPS) * c.z;
      s += __expf((ui + p.w - c.w) * INV_EPS) * c.w;
    }
    s = wave_reduce_sum(s);
    if (lane == 0) wcost += s;
  }
  if (lane == 0) atomicAdd(&s_red, wcost);
  __syncthreads();
  if (tid == 0) atomicAdd(out + b, s_red);
}

extern "C" void kernel_launch(void* const* d_in, const int* in_sizes, int n_in,
                              void* d_out, int out_size, void* d_ws, size_t ws_size,
                              hipStream_t stream) {
  const float* x = (const float*)d_in[0];
  const float* y = (const float*)d_in[1];
  const float* nu = (const float*)d_in[2];
  float* out = (float*)d_out;
  float* ws = (float*)d_ws;

  float* C = ws + OFF_C;
  float* CT = ws + OFF_CT;
  float* nx = ws + OFF_NX;
  float* ny = ws + OFF_NY;
  float* un = ws + OFF_UN;
  float* v = ws + OFF_V;
  float* lnu = ws + OFF_LNU;
  float* err = ws + OFF_ERR;
  int* bar = (int*)(ws + OFF_BAR);

  norms_kernel<<<2048, 256, 0, stream>>>(x, y, nx, ny, nu, v, lnu, err, bar, out);
  gemm_kernel<<<dim3(8, 16, 4), 256, 0, stream>>>(x, y, nx, ny, C, CT);

  void* args[] = {(void*)&C, (void*)&CT, (void*)&un, (void*)&v,
                  (void*)&lnu, (void*)&err, (void*)&bar, (void*)&out};
  hipLaunchCooperativeKernel(reinterpret_cast<void*>(&sinkhorn_kernel),
                             dim3(GBLK), dim3(TBLK), args, 0, stream);
}

// Round 4
// 143.734 us; speedup vs baseline: 2.9169x; 1.0803x over previous
//
#include <hip/hip_runtime.h>
#include <math.h>

#define EPS      0.1f
#define INV_EPS  10.0f
#define THRESH   0.1f
#define MAX_IT   20

// Problem sizes (fixed by reference setup_inputs)
#define BB 4
#define NN 1024
#define MM 1024
#define DD 512

// Sinkhorn loop config: 128 blocks x 512 threads, 32 rows/block, 4 rows/wave
#define GBLK 128
#define TBLK 512

// workspace layout (float offsets). K/KT are bf16 (ushort), 2 per float slot.
#define OFF_K    ((size_t)0)                   // K  = exp(-C/eps) [B,N,M] bf16
#define OFF_KT   ((size_t)2097152)             // KT [B,M,N] bf16
#define OFF_NX   ((size_t)4194304)             // |x_i| [B*N]
#define OFF_NY   (OFF_NX + 4096)               // |y_j| [B*M]
#define OFF_UN   (OFF_NY + 4096)               // u_new [B*N]
#define OFF_V    (OFF_UN + 4096)               // v     [B*M]
#define OFF_LNU  (OFF_V  + 4096)               // log(nu+1e-8) [B*M]
#define OFF_ERRP (OFF_LNU + 4096)              // per-block err partials [128]
#define OFF_BAR  (OFF_ERRP + 128)              // barrier state [256 ints]

typedef __bf16 bf16x8 __attribute__((ext_vector_type(8)));
typedef float f32x4 __attribute__((ext_vector_type(4)));

__device__ __forceinline__ float wave_reduce_sum(float x) {
#pragma unroll
  for (int off = 32; off > 0; off >>= 1) x += __shfl_xor(x, off, 64);
  return x;
}

// -------- norms of x/y rows + init of sinkhorn state (merged) --------
__global__ void __launch_bounds__(256) norms_kernel(const float* __restrict__ x,
                                                    const float* __restrict__ y,
                                                    float* __restrict__ nx,
                                                    float* __restrict__ ny,
                                                    const float* __restrict__ nu,
                                                    float* v, float* log_nu,
                                                    int* bar, float* out) {
  const int tid = threadIdx.x;
  int gt = blockIdx.x * 256 + tid;
  if (gt < BB * MM) {
    v[gt] = 0.f;
    log_nu[gt] = logf(nu[gt] + 1e-8f);
  }
  if (gt < 256) bar[gt] = 0;
  if (gt < BB) out[gt] = 0.f;

  const int w = tid >> 6, lane = tid & 63;
  const int r = blockIdx.x * 4 + w;                 // 0..8191
  const float* src = (r < BB * NN) ? (x + (size_t)r * DD)
                                   : (y + (size_t)(r - BB * NN) * DD);
  const float4* s4 = (const float4*)src;
  float4 a = s4[lane];
  float4 b = s4[lane + 64];
  float ss = a.x * a.x + a.y * a.y + a.z * a.z + a.w * a.w +
             b.x * b.x + b.y * b.y + b.z * b.z + b.w * b.w;
  ss = wave_reduce_sum(ss);
  if (lane == 0) {
    float n = sqrtf(ss);
    if (r < BB * NN) nx[r] = n; else ny[r - BB * NN] = n;
  }
}

// split fp32 -> (hi, lo) bf16 pair by truncation; hi+lo captures ~16 mantissa bits
__device__ __forceinline__ void cvt4(float4 f, uint2& ph, uint2& pl) {
  uint b0 = __float_as_uint(f.x), b1 = __float_as_uint(f.y);
  uint b2 = __float_as_uint(f.z), b3 = __float_as_uint(f.w);
  ph.x = (b0 >> 16) | (b1 & 0xffff0000u);
  ph.y = (b2 >> 16) | (b3 & 0xffff0000u);
  float r0 = f.x - __uint_as_float(b0 & 0xffff0000u);
  float r1 = f.y - __uint_as_float(b1 & 0xffff0000u);
  float r2 = f.z - __uint_as_float(b2 & 0xffff0000u);
  float r3 = f.w - __uint_as_float(b3 & 0xffff0000u);
  pl.x = (__float_as_uint(r0) >> 16) | (__float_as_uint(r1) & 0xffff0000u);
  pl.y = (__float_as_uint(r2) >> 16) | (__float_as_uint(r3) & 0xffff0000u);
}

__device__ __forceinline__ uint pack_bf16_2(float a, float b) {
  __bf16 ha = (__bf16)a, hb = (__bf16)b;
  ushort ua = *(ushort*)&ha, ub = *(ushort*)&hb;
  return (uint)ua | ((uint)ub << 16);
}

// -------- MFMA split-bf16 GEMM: dot = X Y^T (3 passes: hh + hl + lh),
// epilogue K = exp(-(1 - dot/denom)/eps) stored bf16; writes K and KT. --------
__global__ void __launch_bounds__(256) gemm_kernel(const float* __restrict__ x,
                                                   const float* __restrict__ y,
                                                   const float* __restrict__ nxg,
                                                   const float* __restrict__ nyg,
                                                   ushort* __restrict__ K,
                                                   ushort* __restrict__ KT) {
  __shared__ ushort Ah[64 * 32], Al[64 * 32];     // 4 KB each
  __shared__ ushort Bh[128 * 32], Bl[128 * 32];   // 8 KB each
  __shared__ float Tt[32 * 68];                   // transpose staging, 8.5 KB
  __shared__ float s_nx[64], s_ny[128];

  const int b = blockIdx.z;
  const int i0 = blockIdx.y * 64;    // m-tile
  const int j0 = blockIdx.x * 128;   // n-tile
  const int t = threadIdx.x;
  const int w = t >> 6, lane = t & 63;
  const int m16 = lane & 15, q = lane >> 4;
  const int wm = (w & 1) * 32, wn = (w >> 1) * 64;

  const int srow = t >> 3;            // 0..31 staging row within pass
  const int skq = (t & 7) * 4;        // staging k-offset (floats)

  const float* xb = x + ((size_t)b * NN + i0 + srow) * DD + skq;
  const float* yb = y + ((size_t)b * MM + j0 + srow) * DD + skq;

  f32x4 acc[2][4];
#pragma unroll
  for (int mi = 0; mi < 2; ++mi)
#pragma unroll
    for (int ni = 0; ni < 4; ++ni) acc[mi][ni] = (f32x4)0.f;

  for (int k0 = 0; k0 < DD; k0 += 32) {
    float4 ax[2], by[4];
#pragma unroll
    for (int p = 0; p < 2; ++p) ax[p] = *(const float4*)(xb + (size_t)p * 32 * DD + k0);
#pragma unroll
    for (int p = 0; p < 4; ++p) by[p] = *(const float4*)(yb + (size_t)p * 32 * DD + k0);
    __syncthreads();
#pragma unroll
    for (int p = 0; p < 2; ++p) {
      uint2 ph, pl;
      cvt4(ax[p], ph, pl);
      *(uint2*)&Ah[(srow + p * 32) * 32 + skq] = ph;
      *(uint2*)&Al[(srow + p * 32) * 32 + skq] = pl;
    }
#pragma unroll
    for (int p = 0; p < 4; ++p) {
      uint2 ph, pl;
      cvt4(by[p], ph, pl);
      *(uint2*)&Bh[(srow + p * 32) * 32 + skq] = ph;
      *(uint2*)&Bl[(srow + p * 32) * 32 + skq] = pl;
    }
    __syncthreads();

    bf16x8 ahf[2], alf[2], bhf[4], blf[4];
#pragma unroll
    for (int mi = 0; mi < 2; ++mi) {
      const int ai = (wm + mi * 16 + m16) * 32 + q * 8;
      ahf[mi] = *(const bf16x8*)&Ah[ai];
      alf[mi] = *(const bf16x8*)&Al[ai];
    }
#pragma unroll
    for (int ni = 0; ni < 4; ++ni) {
      const int bi = (wn + ni * 16 + m16) * 32 + q * 8;
      bhf[ni] = *(const bf16x8*)&Bh[bi];
      blf[ni] = *(const bf16x8*)&Bl[bi];
    }
#pragma unroll
    for (int mi = 0; mi < 2; ++mi)
#pragma unroll
      for (int ni = 0; ni < 4; ++ni) {
        acc[mi][ni] = __builtin_amdgcn_mfma_f32_16x16x32_bf16(ahf[mi], bhf[ni], acc[mi][ni], 0, 0, 0);
        acc[mi][ni] = __builtin_amdgcn_mfma_f32_16x16x32_bf16(ahf[mi], blf[ni], acc[mi][ni], 0, 0, 0);
        acc[mi][ni] = __builtin_amdgcn_mfma_f32_16x16x32_bf16(alf[mi], bhf[ni], acc[mi][ni], 0, 0, 0);
      }
  }

  // epilogue: K = exp(-(1 - dot/den)/eps), bf16
  if (t < 64) s_nx[t] = nxg[b * NN + i0 + t];
  else if (t < 192) s_ny[t - 64] = nyg[b * MM + j0 + t - 64];
  __syncthreads();

#pragma unroll
  for (int mi = 0; mi < 2; ++mi)
#pragma unroll
    for (int ni = 0; ni < 4; ++ni)
#pragma unroll
      for (int r = 0; r < 4; ++r) {
        const int m = wm + mi * 16 + q * 4 + r;
        const int n = wn + ni * 16 + m16;
        float den = fmaxf(s_nx[m] * s_ny[n], 1e-8f);
        float cv = 1.0f - acc[mi][ni][r] / den;
        float kf = __expf(-cv * INV_EPS);
        acc[mi][ni][r] = kf;
        __bf16 hb = (__bf16)kf;
        K[((size_t)b * NN + i0 + m) * MM + j0 + n] = *(ushort*)&hb;
      }

  // KT via 4-pass LDS transpose (32 n-rows per pass)
#pragma unroll
  for (int p = 0; p < 4; ++p) {
    __syncthreads();
    if ((wn >> 5) == (p & 2)) {          // wn=0 -> p 0,1 ; wn=64 -> p 2,3
      const int ni0 = ((p * 32 - wn) >> 4);
#pragma unroll
      for (int nn2 = 0; nn2 < 2; ++nn2) {
        const int ni = ni0 + nn2;
        const int nl = ni * 16 + m16 - p * 32 + wn;   // 0..31
#pragma unroll
        for (int mi = 0; mi < 2; ++mi)
#pragma unroll
          for (int r = 0; r < 4; ++r)
            Tt[nl * 68 + wm + mi * 16 + q * 4 + r] = acc[mi][ni][r];
      }
    }
    __syncthreads();
    const int row = t >> 3;
    const int off = (t & 7) * 8;
    float4 v0 = *(float4*)&Tt[row * 68 + off];
    float4 v1 = *(float4*)&Tt[row * 68 + off + 4];
    uint4 pk;
    pk.x = pack_bf16_2(v0.x, v0.y);
    pk.y = pack_bf16_2(v0.z, v0.w);
    pk.z = pack_bf16_2(v1.x, v1.y);
    pk.w = pack_bf16_2(v1.z, v1.w);
    *(uint4*)(KT + ((size_t)b * MM + j0 + p * 32 + row) * NN + i0 + off) = pk;
  }
}

// 8 bf16 (packed in uint4 lanes) FMA'd against 8 fp32 weights
__device__ __forceinline__ float fma8(uint4 k, float4 wa, float4 wb, float s) {
  s = fmaf(__uint_as_float(k.x << 16), wa.x, s);
  s = fmaf(__uint_as_float(k.x & 0xffff0000u), wa.y, s);
  s = fmaf(__uint_as_float(k.y << 16), wa.z, s);
  s = fmaf(__uint_as_float(k.y & 0xffff0000u), wa.w, s);
  s = fmaf(__uint_as_float(k.z << 16), wb.x, s);
  s = fmaf(__uint_as_float(k.z & 0xffff0000u), wb.y, s);
  s = fmaf(__uint_as_float(k.w << 16), wb.z, s);
  s = fmaf(__uint_as_float(k.w & 0xffff0000u), wb.w, s);
  return s;
}

// final-cost accumulation: s += k * w * (-eps*log k)  for 8 packed bf16
__device__ __forceinline__ float cost8(uint4 k, float4 wa, float4 wb, float s) {
  uint ks[4] = {k.x, k.y, k.z, k.w};
  float wv[8] = {wa.x, wa.y, wa.z, wa.w, wb.x, wb.y, wb.z, wb.w};
#pragma unroll
  for (int i = 0; i < 4; ++i) {
    float f0 = __uint_as_float(ks[i] << 16);
    float f1 = __uint_as_float(ks[i] & 0xffff0000u);
    s = fmaf(f0 * wv[2 * i], -EPS * __logf(f0), s);
    s = fmaf(f1 * wv[2 * i + 1], -EPS * __logf(f1), s);
  }
  return s;
}

// Store-based grid barrier: each block publishes data (relaxed agent atomics),
// drains vmcnt, then STORES its flag (no RMW contention). Leader wave (block 0)
// polls all 128 flags, optionally reduces the 128 err partials, and releases
// via a packed word rel = 2*gen + conv. No fences -> no L2 invalidates; K/KT
// stay L2-resident.
__device__ __forceinline__ int grid_barrier(int* flags, int* relp,
                                            const float* errpart, int gen,
                                            int bid, int tid, int do_err,
                                            int* s_rel) {
  asm volatile("s_waitcnt vmcnt(0)" ::: "memory");
  __syncthreads();
  if (bid == 0 && tid < 64) {
    const int lane = tid;
    if (lane == 0)
      __hip_atomic_store(flags, gen, __ATOMIC_RELAXED, __HIP_MEMORY_SCOPE_AGENT);
    for (;;) {
      int f0 = __hip_atomic_load(flags + lane, __ATOMIC_RELAXED, __HIP_MEMORY_SCOPE_AGENT);
      int f1 = __hip_atomic_load(flags + 64 + lane, __ATOMIC_RELAXED, __HIP_MEMORY_SCOPE_AGENT);
      if (__all(f0 >= gen && f1 >= gen)) break;
      __builtin_amdgcn_s_sleep(1);
    }
    int rel = gen * 2;
    if (do_err) {
      float e = __hip_atomic_load(errpart + lane, __ATOMIC_RELAXED, __HIP_MEMORY_SCOPE_AGENT) +
                __hip_atomic_load(errpart + 64 + lane, __ATOMIC_RELAXED, __HIP_MEMORY_SCOPE_AGENT);
      e = wave_reduce_sum(e);
      if (e * (1.0f / (float)BB) < THRESH) rel |= 1;
    }
    if (lane == 0) {
      __hip_atomic_store(relp, rel, __ATOMIC_RELAXED, __HIP_MEMORY_SCOPE_AGENT);
      *s_rel = rel;
    }
  } else if (tid == 0) {
    __hip_atomic_store(flags + bid, gen, __ATOMIC_RELAXED, __HIP_MEMORY_SCOPE_AGENT);
    int r;
    for (;;) {
      r = __hip_atomic_load(relp, __ATOMIC_RELAXED, __HIP_MEMORY_SCOPE_AGENT);
      if (r >= gen * 2) break;
      __builtin_amdgcn_s_sleep(1);
    }
    *s_rel = r;
  }
  __syncthreads();
  return *s_rel;
}

// -------- persistent Sinkhorn loop (factored kernel form) + final cost --------
// u_new[i] = eps*log_mu - eps*log( sum_j K_ij * exp(v_j/eps) )
// v_new[j] = eps*log_nu - eps*log( sum_i KT_ji * exp(u_new_i/eps) )
// final: out[b] = sum_ij exp(u_i/eps)*K_ij*exp(v_j/eps) * (-eps*log K_ij)
__global__ void __launch_bounds__(TBLK) sinkhorn_kernel(
    const ushort* __restrict__ K, const ushort* __restrict__ KT,
    float* __restrict__ un, float* __restrict__ v,
    const float* __restrict__ log_nu,
    float* __restrict__ errpart, int* __restrict__ bar, float* __restrict__ out) {
  const int tid = threadIdx.x;
  const int bid = blockIdx.x;
  const int lane = tid & 63;
  const int w = tid >> 6;                 // 0..7
  const int b = bid >> 5;                 // batch (32 blocks per batch)
  const int rbase = (bid & 31) * 32;      // first owned row within batch
  int* flags = bar;
  int* relp = bar + 192;
  int gen = 0;

  __shared__ float sv[1024];
  __shared__ float s_red;
  __shared__ int s_rel;

  const float eps_log_mu = EPS * __logf(1.0f / (float)NN + 1e-8f);
  float u_prev[4] = {0.f, 0.f, 0.f, 0.f};

  for (int it = 0; it < MAX_IT; ++it) {
    // ---- row pass: u_new from v ----
    if (tid == 0) s_red = 0.f;
    for (int q2 = tid; q2 < MM; q2 += TBLK)
      sv[q2] = __expf(INV_EPS *
          __hip_atomic_load(v + b * MM + q2, __ATOMIC_RELAXED, __HIP_MEMORY_SCOPE_AGENT));
    __syncthreads();

    const float4* wp = (const float4*)sv;
    float4 w0 = wp[lane * 2], w1 = wp[lane * 2 + 1];
    float4 w2 = wp[lane * 2 + 128], w3 = wp[lane * 2 + 129];

    float werr = 0.f;
#pragma unroll
    for (int rr = 0; rr < 4; ++rr) {
      const int r = rbase + w * 4 + rr;
      const uint4* kp = (const uint4*)(K + ((size_t)b * NN + r) * MM);
      float s = fma8(kp[lane], w0, w1, 0.f);
      s = fma8(kp[lane + 64], w2, w3, s);
      s = wave_reduce_sum(s);
      float unv = eps_log_mu - EPS * __logf(s);
      werr += fabsf(unv - u_prev[rr]);
      u_prev[rr] = unv;
      if (lane == 0)
        __hip_atomic_store(un + b * NN + r, unv, __ATOMIC_RELAXED, __HIP_MEMORY_SCOPE_AGENT);
    }
    if (lane == 0) atomicAdd(&s_red, werr);
    __syncthreads();
    if (tid == 0)
      __hip_atomic_store(errpart + bid, s_red, __ATOMIC_RELAXED, __HIP_MEMORY_SCOPE_AGENT);

    const int conv = grid_barrier(flags, relp, errpart, ++gen, bid, tid, 1, &s_rel) & 1;

    // ---- col pass: v from u_new ----
    for (int q2 = tid; q2 < NN; q2 += TBLK)
      sv[q2] = __expf(INV_EPS *
          __hip_atomic_load(un + b * NN + q2, __ATOMIC_RELAXED, __HIP_MEMORY_SCOPE_AGENT));
    __syncthreads();

    float4 u0 = wp[lane * 2], u1 = wp[lane * 2 + 1];
    float4 u2 = wp[lane * 2 + 128], u3 = wp[lane * 2 + 129];

#pragma unroll
    for (int rr = 0; rr < 4; ++rr) {
      const int c = rbase + w * 4 + rr;
      const uint4* kp = (const uint4*)(KT + ((size_t)b * MM + c) * NN);
      float s = fma8(kp[lane], u0, u1, 0.f);
      s = fma8(kp[lane + 64], u2, u3, s);
      s = wave_reduce_sum(s);
      if (lane == 0) {
        float vv = EPS * log_nu[b * MM + c] - EPS * __logf(s);
        __hip_atomic_store(v + b * MM + c, vv, __ATOMIC_RELAXED, __HIP_MEMORY_SCOPE_AGENT);
      }
    }

    grid_barrier(flags, relp, errpart, ++gen, bid, tid, 0, &s_rel);   // publish v

    if (conv) break;
    __syncthreads();   // protect sv before next iteration's restage
  }

  // ---- final cost ----
  if (tid == 0) s_red = 0.f;
  __syncthreads();
  for (int q2 = tid; q2 < MM; q2 += TBLK)
    sv[q2] = __expf(INV_EPS *
        __hip_atomic_load(v + b * MM + q2, __ATOMIC_RELAXED, __HIP_MEMORY_SCOPE_AGENT));
  __syncthreads();

  const float4* wp = (const float4*)sv;
  float4 w0 = wp[lane * 2], w1 = wp[lane * 2 + 1];
  float4 w2 = wp[lane * 2 + 128], w3 = wp[lane * 2 + 129];

  float wcost = 0.f;
#pragma unroll
  for (int rr = 0; rr < 4; ++rr) {
    const int r = rbase + w * 4 + rr;
    const float wu = __expf(INV_EPS * u_prev[rr]);
    const uint4* kp = (const uint4*)(K + ((size_t)b * NN + r) * MM);
    float s = cost8(kp[lane], w0, w1, 0.f);
    s = cost8(kp[lane + 64], w2, w3, s);
    s = wave_reduce_sum(s) * wu;
    if (lane == 0) wcost += s;
  }
  if (lane == 0) atomicAdd(&s_red, wcost);
  __syncthreads();
  if (tid == 0) atomicAdd(out + b, s_red);
}

extern "C" void kernel_launch(void* const* d_in, const int* in_sizes, int n_in,
                              void* d_out, int out_size, void* d_ws, size_t ws_size,
                              hipStream_t stream) {
  const float* x = (const float*)d_in[0];
  const float* y = (const float*)d_in[1];
  const float* nu = (const float*)d_in[2];
  float* out = (float*)d_out;
  float* ws = (float*)d_ws;

  ushort* K = (ushort*)(ws + OFF_K);
  ushort* KT = (ushort*)(ws + OFF_KT);
  float* nx = ws + OFF_NX;
  float* ny = ws + OFF_NY;
  float* un = ws + OFF_UN;
  float* v = ws + OFF_V;
  float* lnu = ws + OFF_LNU;
  float* errp = ws + OFF_ERRP;
  int* bar = (int*)(ws + OFF_BAR);

  norms_kernel<<<2048, 256, 0, stream>>>(x, y, nx, ny, nu, v, lnu, bar, out);
  gemm_kernel<<<dim3(8, 16, 4), 256, 0, stream>>>(x, y, nx, ny, K, KT);

  void* args[] = {(void*)&K, (void*)&KT, (void*)&un, (void*)&v,
                  (void*)&lnu, (void*)&errp, (void*)&bar, (void*)&out};
  hipLaunchCooperativeKernel(reinterpret_cast<void*>(&sinkhorn_kernel),
                             dim3(GBLK), dim3(TBLK), args, 0, stream);
}

// Round 5
// 130.344 us; speedup vs baseline: 3.2165x; 1.1027x over previous
//
#include <hip/hip_runtime.h>
#include <math.h>

#define EPS      0.1f
#define INV_EPS  10.0f
#define THRESH   0.1f
#define MAX_IT   20

// Problem sizes (fixed by reference setup_inputs)
#define BB 4
#define NN 1024
#define MM 1024
#define DD 512

#define MU_P (1.0f / 1024.0f + 1e-8f)

// Sinkhorn loop config: 128 blocks x 512 threads, 32 rows/block, 4 rows/wave
#define GBLK 128
#define TBLK 512

// workspace layout (float offsets)
#define OFF_K    ((size_t)0)                   // K = exp(-C/eps) [B,N,M] bf16 (8.4 MB)
#define OFF_NX   ((size_t)2097152)             // |x_i| [B*N]
#define OFF_NY   (OFF_NX + 4096)               // |y_j| [B*M]
#define OFF_NUP  (OFF_NY + 4096)               // nu + 1e-8 [B*M]
#define OFF_CS   (OFF_NUP + 4096)              // colsum rotation [3][4096]
#define OFF_FLG  (OFF_CS + 12288)              // barrier flags [2][128] ulong

typedef __bf16 bf16x8 __attribute__((ext_vector_type(8)));
typedef float f32x4 __attribute__((ext_vector_type(4)));
typedef unsigned long long u64;

__device__ __forceinline__ float wave_reduce_sum(float x) {
#pragma unroll
  for (int off = 32; off > 0; off >>= 1) x += __shfl_xor(x, off, 64);
  return x;
}

// -------- norms of x/y rows + init of sinkhorn state (merged) --------
__global__ void __launch_bounds__(256) norms_kernel(const float* __restrict__ x,
                                                    const float* __restrict__ y,
                                                    float* __restrict__ nx,
                                                    float* __restrict__ ny,
                                                    const float* __restrict__ nu,
                                                    float* nup, float* colsum,
                                                    int* flagsi, float* out) {
  const int tid = threadIdx.x;
  int gt = blockIdx.x * 256 + tid;
  if (gt < BB * MM) {
    nup[gt] = nu[gt] + 1e-8f;
    colsum[4096 + gt] = 0.f;      // colsum[1] is iteration 0's add target
  }
  if (gt < 512) flagsi[gt] = 0;   // 2 x 128 ulong flag slots
  if (gt < BB) out[gt] = 0.f;

  const int w = tid >> 6, lane = tid & 63;
  const int r = blockIdx.x * 4 + w;                 // 0..8191
  const float* src = (r < BB * NN) ? (x + (size_t)r * DD)
                                   : (y + (size_t)(r - BB * NN) * DD);
  const float4* s4 = (const float4*)src;
  float4 a = s4[lane];
  float4 b = s4[lane + 64];
  float ss = a.x * a.x + a.y * a.y + a.z * a.z + a.w * a.w +
             b.x * b.x + b.y * b.y + b.z * b.z + b.w * b.w;
  ss = wave_reduce_sum(ss);
  if (lane == 0) {
    float n = sqrtf(ss);
    if (r < BB * NN) nx[r] = n; else ny[r - BB * NN] = n;
  }
}

// split fp32 -> (hi, lo) bf16 pair by truncation; hi+lo captures ~16 mantissa bits
__device__ __forceinline__ void cvt4(float4 f, uint2& ph, uint2& pl) {
  uint b0 = __float_as_uint(f.x), b1 = __float_as_uint(f.y);
  uint b2 = __float_as_uint(f.z), b3 = __float_as_uint(f.w);
  ph.x = (b0 >> 16) | (b1 & 0xffff0000u);
  ph.y = (b2 >> 16) | (b3 & 0xffff0000u);
  float r0 = f.x - __uint_as_float(b0 & 0xffff0000u);
  float r1 = f.y - __uint_as_float(b1 & 0xffff0000u);
  float r2 = f.z - __uint_as_float(b2 & 0xffff0000u);
  float r3 = f.w - __uint_as_float(b3 & 0xffff0000u);
  pl.x = (__float_as_uint(r0) >> 16) | (__float_as_uint(r1) & 0xffff0000u);
  pl.y = (__float_as_uint(r2) >> 16) | (__float_as_uint(r3) & 0xffff0000u);
}

// -------- MFMA split-bf16 GEMM: dot = X Y^T (3 passes: hh + hl + lh),
// epilogue K = exp(-(1 - dot/denom)/eps) stored bf16 (row-major only). --------
__global__ void __launch_bounds__(256) gemm_kernel(const float* __restrict__ x,
                                                   const float* __restrict__ y,
                                                   const float* __restrict__ nxg,
                                                   const float* __restrict__ nyg,
                                                   ushort* __restrict__ K) {
  __shared__ ushort Ah[64 * 32], Al[64 * 32];     // 4 KB each
  __shared__ ushort Bh[128 * 32], Bl[128 * 32];   // 8 KB each
  __shared__ float s_nx[64], s_ny[128];

  const int b = blockIdx.z;
  const int i0 = blockIdx.y * 64;    // m-tile
  const int j0 = blockIdx.x * 128;   // n-tile
  const int t = threadIdx.x;
  const int w = t >> 6, lane = t & 63;
  const int m16 = lane & 15, q = lane >> 4;
  const int wm = (w & 1) * 32, wn = (w >> 1) * 64;

  const int srow = t >> 3;            // 0..31 staging row within pass
  const int skq = (t & 7) * 4;        // staging k-offset (floats)

  const float* xb = x + ((size_t)b * NN + i0 + srow) * DD + skq;
  const float* yb = y + ((size_t)b * MM + j0 + srow) * DD + skq;

  f32x4 acc[2][4];
#pragma unroll
  for (int mi = 0; mi < 2; ++mi)
#pragma unroll
    for (int ni = 0; ni < 4; ++ni) acc[mi][ni] = (f32x4)0.f;

  for (int k0 = 0; k0 < DD; k0 += 32) {
    float4 ax[2], by[4];
#pragma unroll
    for (int p = 0; p < 2; ++p) ax[p] = *(const float4*)(xb + (size_t)p * 32 * DD + k0);
#pragma unroll
    for (int p = 0; p < 4; ++p) by[p] = *(const float4*)(yb + (size_t)p * 32 * DD + k0);
    __syncthreads();
#pragma unroll
    for (int p = 0; p < 2; ++p) {
      uint2 ph, pl;
      cvt4(ax[p], ph, pl);
      *(uint2*)&Ah[(srow + p * 32) * 32 + skq] = ph;
      *(uint2*)&Al[(srow + p * 32) * 32 + skq] = pl;
    }
#pragma unroll
    for (int p = 0; p < 4; ++p) {
      uint2 ph, pl;
      cvt4(by[p], ph, pl);
      *(uint2*)&Bh[(srow + p * 32) * 32 + skq] = ph;
      *(uint2*)&Bl[(srow + p * 32) * 32 + skq] = pl;
    }
    __syncthreads();

    bf16x8 ahf[2], alf[2], bhf[4], blf[4];
#pragma unroll
    for (int mi = 0; mi < 2; ++mi) {
      const int ai = (wm + mi * 16 + m16) * 32 + q * 8;
      ahf[mi] = *(const bf16x8*)&Ah[ai];
      alf[mi] = *(const bf16x8*)&Al[ai];
    }
#pragma unroll
    for (int ni = 0; ni < 4; ++ni) {
      const int bi = (wn + ni * 16 + m16) * 32 + q * 8;
      bhf[ni] = *(const bf16x8*)&Bh[bi];
      blf[ni] = *(const bf16x8*)&Bl[bi];
    }
#pragma unroll
    for (int mi = 0; mi < 2; ++mi)
#pragma unroll
      for (int ni = 0; ni < 4; ++ni) {
        acc[mi][ni] = __builtin_amdgcn_mfma_f32_16x16x32_bf16(ahf[mi], bhf[ni], acc[mi][ni], 0, 0, 0);
        acc[mi][ni] = __builtin_amdgcn_mfma_f32_16x16x32_bf16(ahf[mi], blf[ni], acc[mi][ni], 0, 0, 0);
        acc[mi][ni] = __builtin_amdgcn_mfma_f32_16x16x32_bf16(alf[mi], bhf[ni], acc[mi][ni], 0, 0, 0);
      }
  }

  // epilogue: K = exp(-(1 - dot/den)/eps), bf16
  if (t < 64) s_nx[t] = nxg[b * NN + i0 + t];
  else if (t < 192) s_ny[t - 64] = nyg[b * MM + j0 + t - 64];
  __syncthreads();

#pragma unroll
  for (int mi = 0; mi < 2; ++mi)
#pragma unroll
    for (int ni = 0; ni < 4; ++ni)
#pragma unroll
      for (int r = 0; r < 4; ++r) {
        const int m = wm + mi * 16 + q * 4 + r;
        const int n = wn + ni * 16 + m16;
        float den = fmaxf(s_nx[m] * s_ny[n], 1e-8f);
        float cv = 1.0f - acc[mi][ni][r] / den;
        float kf = __expf(-cv * INV_EPS);
        __bf16 hb = (__bf16)kf;
        K[((size_t)b * NN + i0 + m) * MM + j0 + n] = *(ushort*)&hb;
      }
}

__device__ __forceinline__ void unpack8(uint4 k, float* kf) {
  kf[0] = __uint_as_float(k.x << 16);
  kf[1] = __uint_as_float(k.x & 0xffff0000u);
  kf[2] = __uint_as_float(k.y << 16);
  kf[3] = __uint_as_float(k.y & 0xffff0000u);
  kf[4] = __uint_as_float(k.z << 16);
  kf[5] = __uint_as_float(k.z & 0xffff0000u);
  kf[6] = __uint_as_float(k.w << 16);
  kf[7] = __uint_as_float(k.w & 0xffff0000u);
}

// -------- persistent Sinkhorn, ONE barrier per iteration --------
// rowsum_i = sum_j K_ij wv_j ; u_i = eps(log mu' - log rowsum_i); wu_i = mu'/rowsum_i
// colsum_j = sum_i K_ij wu_i (atomic-accumulated grid-wide, 3-buffer rotation)
// wv_j = nu'_j / colsum_j (recomputed LOCALLY by every block -> no v-barrier)
// barrier: all-to-all, one ulong {gen, err} per block, depth-2 ping-pong slots.
__global__ void __launch_bounds__(TBLK) sinkhorn_kernel(
    const ushort* __restrict__ K, float* __restrict__ colsum,
    const float* __restrict__ nup, u64* __restrict__ flags,
    float* __restrict__ out) {
  const int tid = threadIdx.x;
  const int bid = blockIdx.x;
  const int lane = tid & 63;
  const int w = tid >> 6;                 // 0..7
  const int b = bid >> 5;                 // batch (32 blocks per batch)
  const int rbase = (bid & 31) * 32;      // first owned row within batch

  __shared__ float swv[1024];
  __shared__ float spart[8][1024];        // 32 KB per-wave column partials
  __shared__ float s_red;
  __shared__ int s_conv;

  const float eps_log_mu = EPS * __logf(MU_P);
  float u_prev[4] = {0.f, 0.f, 0.f, 0.f};
  float wu_reg[4] = {0.f, 0.f, 0.f, 0.f};
  int T = 0;

  for (int it = 0; it < MAX_IT; ++it) {
    const int genv = it + 1;
    // ---- stage wv (local v reconstruction; it=0: v=0 -> wv=1) ----
    if (tid == 0) s_red = 0.f;
    if (it == 0) {
      swv[tid] = 1.f;
      swv[tid + 512] = 1.f;
    } else {
      const float* cs = colsum + (it % 3) * 4096 + b * MM;
      float c0 = __hip_atomic_load(cs + tid, __ATOMIC_RELAXED, __HIP_MEMORY_SCOPE_AGENT);
      float c1 = __hip_atomic_load(cs + tid + 512, __ATOMIC_RELAXED, __HIP_MEMORY_SCOPE_AGENT);
      swv[tid] = nup[b * MM + tid] / c0;
      swv[tid + 512] = nup[b * MM + tid + 512] / c1;
    }
    __syncthreads();

    float wvr[16];
    {
      const float4* wp = (const float4*)swv;
      *(float4*)&wvr[0] = wp[lane * 2];
      *(float4*)&wvr[4] = wp[lane * 2 + 1];
      *(float4*)&wvr[8] = wp[128 + lane * 2];
      *(float4*)&wvr[12] = wp[129 + lane * 2];
    }
    float creg[16];
#pragma unroll
    for (int t2 = 0; t2 < 16; ++t2) creg[t2] = 0.f;

    // preload this wave's 4 K-rows (L2-resident)
    uint4 kq[4][2];
#pragma unroll
    for (int rr = 0; rr < 4; ++rr) {
      const uint4* kp = (const uint4*)(K + ((size_t)b * NN + rbase + w * 4 + rr) * MM);
      kq[rr][0] = kp[lane];
      kq[rr][1] = kp[lane + 64];
    }

    float werr = 0.f;
#pragma unroll
    for (int rr = 0; rr < 4; ++rr) {
      float kf[16];
      unpack8(kq[rr][0], kf);
      unpack8(kq[rr][1], kf + 8);
      float s = 0.f;
#pragma unroll
      for (int t2 = 0; t2 < 16; ++t2) s = fmaf(kf[t2], wvr[t2], s);
      s = wave_reduce_sum(s);
      float unv = eps_log_mu - EPS * __logf(s);
      werr += fabsf(unv - u_prev[rr]);
      u_prev[rr] = unv;
      float wu = MU_P / s;          // exp(u_new/eps), exactly
      wu_reg[rr] = wu;
#pragma unroll
      for (int t2 = 0; t2 < 16; ++t2) creg[t2] = fmaf(wu, kf[t2], creg[t2]);
    }
    if (lane == 0) atomicAdd(&s_red, werr);

    // publish per-wave column partials to LDS
    {
      float* pr = &spart[w][0];
      *(float4*)&pr[lane * 8] = *(float4*)&creg[0];
      *(float4*)&pr[lane * 8 + 4] = *(float4*)&creg[4];
      *(float4*)&pr[512 + lane * 8] = *(float4*)&creg[8];
      *(float4*)&pr[512 + lane * 8 + 4] = *(float4*)&creg[12];
    }
    __syncthreads();

    // cross-wave reduce + atomic add into next colsum; zero rotation buffer
    {
      float* csn = colsum + ((it + 1) % 3) * 4096 + b * MM;
      const int j0 = tid * 2;
      float s0 = 0.f, s1 = 0.f;
#pragma unroll
      for (int ww = 0; ww < 8; ++ww) {
        float2 p = *(const float2*)&spart[ww][j0];
        s0 += p.x;
        s1 += p.y;
      }
      unsafeAtomicAdd(&csn[j0], s0);
      unsafeAtomicAdd(&csn[j0 + 1], s1);
      if (tid < 32) {
        float* csz = colsum + ((it + 2) % 3) * 4096;
        __hip_atomic_store(&csz[bid * 32 + tid], 0.f, __ATOMIC_RELAXED, __HIP_MEMORY_SCOPE_AGENT);
      }
    }

    // ---- all-to-all barrier: publish {gen, err}, poll, local conv decision ----
    asm volatile("s_waitcnt vmcnt(0)" ::: "memory");
    __syncthreads();
    if (tid == 0) {
      u64 f = ((u64)(uint)genv << 32) | (u64)__float_as_uint(s_red);
      __hip_atomic_store(&flags[(genv & 1) * GBLK + bid], f, __ATOMIC_RELAXED, __HIP_MEMORY_SCOPE_AGENT);
    }
    if (tid < 64) {
      const u64* fl = flags + (genv & 1) * GBLK;
      u64 f0, f1;
      for (;;) {
        f0 = __hip_atomic_load(fl + tid, __ATOMIC_RELAXED, __HIP_MEMORY_SCOPE_AGENT);
        f1 = __hip_atomic_load(fl + tid + 64, __ATOMIC_RELAXED, __HIP_MEMORY_SCOPE_AGENT);
        if (__all(((f0 >> 32) >= (u64)genv) && ((f1 >> 32) >= (u64)genv))) break;
        __builtin_amdgcn_s_sleep(1);
      }
      float e = __uint_as_float((uint)f0) + __uint_as_float((uint)f1);
      e = wave_reduce_sum(e);
      if (tid == 0) s_conv = (e * (1.0f / (float)BB) < THRESH) ? 1 : 0;
    }
    __syncthreads();
    T = it;
    if (s_conv) break;
  }

  // ---- final: reconstruct converged wv locally, accumulate transport cost ----
  {
    const float* cs = colsum + ((T + 1) % 3) * 4096 + b * MM;
    float c0 = __hip_atomic_load(cs + tid, __ATOMIC_RELAXED, __HIP_MEMORY_SCOPE_AGENT);
    float c1 = __hip_atomic_load(cs + tid + 512, __ATOMIC_RELAXED, __HIP_MEMORY_SCOPE_AGENT);
    swv[tid] = nup[b * MM + tid] / c0;
    swv[tid + 512] = nup[b * MM + tid + 512] / c1;
  }
  if (tid == 0) s_red = 0.f;
  __syncthreads();

  float wvr[16];
  {
    const float4* wp = (const float4*)swv;
    *(float4*)&wvr[0] = wp[lane * 2];
    *(float4*)&wvr[4] = wp[lane * 2 + 1];
    *(float4*)&wvr[8] = wp[128 + lane * 2];
    *(float4*)&wvr[12] = wp[129 + lane * 2];
  }

  float wcost = 0.f;
#pragma unroll
  for (int rr = 0; rr < 4; ++rr) {
    const int r = rbase + w * 4 + rr;
    const uint4* kp = (const uint4*)(K + ((size_t)b * NN + r) * MM);
    uint4 k0 = kp[lane], k1 = kp[lane + 64];
    float kf[16];
    unpack8(k0, kf);
    unpack8(k1, kf + 8);
    float s = 0.f;
#pragma unroll
    for (int t2 = 0; t2 < 16; ++t2)
      s = fmaf(kf[t2] * wvr[t2], -EPS * __logf(kf[t2]), s);   // pi * C, C = -eps log K
    s = wave_reduce_sum(s) * wu_reg[rr];
    if (lane == 0) wcost += s;
  }
  if (lane == 0) atomicAdd(&s_red, wcost);
  __syncthreads();
  if (tid == 0) atomicAdd(out + b, s_red);
}

extern "C" void kernel_launch(void* const* d_in, const int* in_sizes, int n_in,
                              void* d_out, int out_size, void* d_ws, size_t ws_size,
                              hipStream_t stream) {
  const float* x = (const float*)d_in[0];
  const float* y = (const float*)d_in[1];
  const float* nu = (const float*)d_in[2];
  float* out = (float*)d_out;
  float* ws = (float*)d_ws;

  ushort* K = (ushort*)(ws + OFF_K);
  float* nx = ws + OFF_NX;
  float* ny = ws + OFF_NY;
  float* nup = ws + OFF_NUP;
  float* cs = ws + OFF_CS;
  u64* flg = (u64*)(ws + OFF_FLG);

  norms_kernel<<<2048, 256, 0, stream>>>(x, y, nx, ny, nu, nup, cs, (int*)flg, out);
  gemm_kernel<<<dim3(8, 16, 4), 256, 0, stream>>>(x, y, nx, ny, K);

  void* args[] = {(void*)&K, (void*)&cs, (void*)&nup, (void*)&flg, (void*)&out};
  hipLaunchCooperativeKernel(reinterpret_cast<void*>(&sinkhorn_kernel),
                             dim3(GBLK), dim3(TBLK), args, 0, stream);
}